// Round 10
// baseline (89.845 us; speedup 1.0000x reference)
//
#include <hip/hip_runtime.h>
#include <stdint.h>
#include <stddef.h>

typedef __attribute__((ext_vector_type(4))) float    f32x4;
typedef __attribute__((ext_vector_type(4))) uint32_t u32x4;
typedef __attribute__((ext_vector_type(8))) __bf16   bf16x8;

#define CGS   5248      // 5248 % 512 == 128; same 41984B LDS allocation as 5200, fewer conflicts (R6)
#define NFRAG 15360     // 15 (dir,tap) * 2 kk * 4 mtile * 64 lanes
#define GRID  768       // 3 blocks/CU, all resident; blocks 0-511 do 3 batches, 512-767 do 2

// tap (kr,kc) per f = dir*5+tap  (dir: 0=up,1=left,2=right)
__device__ __constant__ uint8_t TAPR[15] = {0,0,1,2,2, 1,2,2,2,3, 1,2,2,2,3};
__device__ __constant__ uint8_t TAPC[15] = {0,1,1,1,2, 1,0,1,2,1, 1,1,2,3,3};

// periodic-boundary copies on padded 18x18 (dst <- src), sources never destinations
__device__ __constant__ uint8_t PDR[30] = {1,1,2,3,4,4,6,7,8,10,11,12,14,14,15,16,17,17,16,15,14,14,12,10,8,6,4,4,3,2};
__device__ __constant__ uint8_t PDC[30] = {3,5,7,9,10,11,13,13,14,15,15,16,15,16,15,14,13,11,9,7,6,5,3,2,1,0,0,1,1,2};
__device__ __constant__ uint8_t PSR[30] = {13,13,14,15,16,16,6,7,8,10,11,12,2,2,3,4,5,5,4,3,2,2,12,10,8,6,16,16,15,14};
__device__ __constant__ uint8_t PSC[30] = {15,5,7,9,10,11,1,1,2,3,3,4,3,4,3,2,1,11,9,7,6,5,15,14,13,12,12,13,13,14};

__device__ __forceinline__ uint32_t pk2(float a, float b) {
    return (uint32_t)__builtin_bit_cast(uint16_t, (__bf16)a)
         | ((uint32_t)__builtin_bit_cast(uint16_t, (__bf16)b) << 16);
}

// ---------------- weight packing: A-fragment layout for mfma_f32_16x16x32_bf16 ----------------
__global__ __launch_bounds__(256) void pack_w(const float* __restrict__ wu,
                                              const float* __restrict__ wl,
                                              const float* __restrict__ wr,
                                              uint16_t* __restrict__ pw) {
    int fid = blockIdx.x * 256 + threadIdx.x;
    if (fid >= NFRAG) return;
    int lane = fid & 63;
    int mt   = (fid >> 6) & 3;
    int kk   = (fid >> 8) & 1;
    int td   = fid >> 9;                 // 0..14 = dir*5+tap
    const float* w = (td < 5) ? wu : (td < 10) ? wl : wr;
    int o  = mt * 16 + (lane & 15);
    int cb = kk * 32 + (lane >> 4) * 8;
    int kr = TAPR[td], kc = TAPC[td];
    const float* src = w + ((size_t)o * 64 + cb) * 16 + kr * 4 + kc;
    uint32_t d[4];
#pragma unroll
    for (int p = 0; p < 4; ++p)
        d[p] = pk2(src[(2 * p) * 16], src[(2 * p + 1) * 16]);
    u32x4 v = {d[0], d[1], d[2], d[3]};
    *(u32x4*)(pw + (size_t)fid * 8) = v;
}

// slot within a channel-group plane, column-parity split: 16 B per slot (8 channels, one pixel)
__device__ __forceinline__ int slotof(int r, int c) { return (c & 1) * 162 + r * 9 + (c >> 1); }

__global__ __launch_bounds__(256, 3) void kagome_main(const float* __restrict__ x,
                                                      const uint16_t* __restrict__ pw,
                                                      const float* __restrict__ bu,
                                                      const float* __restrict__ bl,
                                                      const float* __restrict__ br,
                                                      float* __restrict__ out,
                                                      int B) {
    __shared__ __align__(16) uint8_t lds[8 * CGS];
    const int tid = threadIdx.x;
    const int bid = blockIdx.x;

    // work split: blocks [0, x3) do 3 consecutive batches, rest do 2
    const int x3   = B - 2 * GRID;                   // 512 for B=2048
    const int nb   = (bid < x3) ? 3 : 2;
    const int base = (bid < x3) ? bid * 3 : x3 * 3 + (bid - x3) * 2;

    // compute lane decomposition
    const int l   = tid & 63;
    const int wid = tid >> 6;
    const int q   = l >> 4;        // k-quarter
    const int io  = (l >> 3) & 1;  // row-pair within n-tile
    const int j   = l & 7;         // conv output column

    // hoisted bias loads
    const int ob = wid * 16 + q * 4;
    f32x4 bias0 = *(const f32x4*)(bu + ob);
    f32x4 bias1 = *(const f32x4*)(bl + ob);
    f32x4 bias2 = *(const f32x4*)(br + ob);

    const int bbase = q * CGS + io * 288 + j * 16;
    const uint16_t* pwl = pw + (size_t)l * 8;

    constexpr uint32_t RM[16] = {0x0008, 0x003C, 0x00FC, 0x01FE, 0x07FF, 0x0FFF, 0x0FFF, 0x1FFE,
                                 0x3FFE, 0xBFFC, 0xBFFC, 0x7FF8, 0xFFF0, 0x3FC0, 0x3F80, 0x1E00};
    const int odd = j & 1;

    // ---- zero all 68 border sites ONCE (copy-dst sites get rewritten each iter;
    //      pure-zero border sites are never written again) ----
    {
        u32x4 z = {0, 0, 0, 0};
        for (int idx = tid; idx < 68 * 8; idx += 256) {
            int s = idx >> 3, cg = idx & 7;
            int r, c;
            if (s < 18)      { r = 0;  c = s; }
            else if (s < 36) { r = 17; c = s - 18; }
            else             { int k2 = s - 36; r = 1 + (k2 >> 1); c = (k2 & 1) * 17; }
            *(u32x4*)(lds + cg * CGS + slotof(r, c) * 16) = z;
        }
    }

    for (int it = 0; it < nb; ++it) {
        const int b = base + it;

        // ---- stage interior (16x16) as bf16; stores of prev iter still in flight ----
        {
            const float* xb = x + (size_t)b * 16384;
#pragma unroll
            for (int i = 0; i < 2; ++i) {
                const int t    = i * 256 + tid;
                const int cg   = t >> 6;
                const int quad = t & 63;
                const int r0   = quad >> 2;
                const int qc   = quad & 3;
                f32x4 v[8];
#pragma unroll
                for (int ch = 0; ch < 8; ++ch)
                    v[ch] = *(const f32x4*)(xb + (cg * 8 + ch) * 256 + quad * 4);
                uint8_t* base_p = lds + cg * CGS;
#pragma unroll
                for (int e = 0; e < 4; ++e) {
                    const int slot = slotof(r0 + 1, 4 * qc + e + 1);
                    u32x4 w = {pk2(v[0][e], v[1][e]), pk2(v[2][e], v[3][e]),
                               pk2(v[4][e], v[5][e]), pk2(v[6][e], v[7][e])};
                    *(u32x4*)(base_p + slot * 16) = w;
                }
            }
        }
        __syncthreads();
        // ---- periodic copies ----
        if (tid < 240) {
            int pair = tid >> 3, cg = tid & 7;
            u32x4 v = *(const u32x4*)(lds + cg * CGS + slotof(PSR[pair], PSC[pair]) * 16);
            *(u32x4*)(lds + cg * CGS + slotof(PDR[pair], PDC[pair]) * 16) = v;
        }
        __syncthreads();

        // ---- compute ----
        f32x4 acc[3][4];
#pragma unroll
        for (int d2 = 0; d2 < 3; ++d2)
#pragma unroll
            for (int n2 = 0; n2 < 4; ++n2) acc[d2][n2] = (f32x4){0.f, 0.f, 0.f, 0.f};

#define BRD(dr, dc) __builtin_bit_cast(bf16x8, *(const u32x4*)(lb + ((dc) & 1) * 2592 + (4 * nt + (dr)) * 144 + ((dc) >> 1) * 16))
#define DO_MFMAS()                                                                             \
            bf16x8 b00 = BRD(0, 0);                                                            \
            acc[0][nt] = __builtin_amdgcn_mfma_f32_16x16x32_bf16(aw[0], b00, acc[0][nt], 0, 0, 0); \
            bf16x8 b01 = BRD(0, 1);                                                            \
            acc[0][nt] = __builtin_amdgcn_mfma_f32_16x16x32_bf16(aw[1], b01, acc[0][nt], 0, 0, 0); \
            bf16x8 b11 = BRD(1, 1);                                                            \
            acc[0][nt] = __builtin_amdgcn_mfma_f32_16x16x32_bf16(aw[2],  b11, acc[0][nt], 0, 0, 0); \
            acc[1][nt] = __builtin_amdgcn_mfma_f32_16x16x32_bf16(aw[5],  b11, acc[1][nt], 0, 0, 0); \
            acc[2][nt] = __builtin_amdgcn_mfma_f32_16x16x32_bf16(aw[10], b11, acc[2][nt], 0, 0, 0); \
            bf16x8 b20 = BRD(2, 0);                                                            \
            acc[1][nt] = __builtin_amdgcn_mfma_f32_16x16x32_bf16(aw[6],  b20, acc[1][nt], 0, 0, 0); \
            bf16x8 b21 = BRD(2, 1);                                                            \
            acc[0][nt] = __builtin_amdgcn_mfma_f32_16x16x32_bf16(aw[3],  b21, acc[0][nt], 0, 0, 0); \
            acc[1][nt] = __builtin_amdgcn_mfma_f32_16x16x32_bf16(aw[7],  b21, acc[1][nt], 0, 0, 0); \
            acc[2][nt] = __builtin_amdgcn_mfma_f32_16x16x32_bf16(aw[11], b21, acc[2][nt], 0, 0, 0); \
            bf16x8 b22 = BRD(2, 2);                                                            \
            acc[0][nt] = __builtin_amdgcn_mfma_f32_16x16x32_bf16(aw[4],  b22, acc[0][nt], 0, 0, 0); \
            acc[1][nt] = __builtin_amdgcn_mfma_f32_16x16x32_bf16(aw[8],  b22, acc[1][nt], 0, 0, 0); \
            acc[2][nt] = __builtin_amdgcn_mfma_f32_16x16x32_bf16(aw[12], b22, acc[2][nt], 0, 0, 0); \
            bf16x8 b23 = BRD(2, 3);                                                            \
            acc[2][nt] = __builtin_amdgcn_mfma_f32_16x16x32_bf16(aw[13], b23, acc[2][nt], 0, 0, 0); \
            bf16x8 b31 = BRD(3, 1);                                                            \
            acc[1][nt] = __builtin_amdgcn_mfma_f32_16x16x32_bf16(aw[9],  b31, acc[1][nt], 0, 0, 0); \
            bf16x8 b33 = BRD(3, 3);                                                            \
            acc[2][nt] = __builtin_amdgcn_mfma_f32_16x16x32_bf16(aw[14], b33, acc[2][nt], 0, 0, 0);

        // kk = 0: pure MFMA
        {
            bf16x8 aw[15];
#pragma unroll
            for (int f2 = 0; f2 < 15; ++f2) {
                u32x4 t = *(const u32x4*)(pwl + (size_t)((f2 * 2 + 0) * 4 + wid) * 512);
                aw[f2] = __builtin_bit_cast(bf16x8, t);
            }
            const uint8_t* lb = lds + bbase;
#pragma unroll
            for (int nt = 0; nt < 4; ++nt) {
                DO_MFMAS()
            }
        }
        // kk = 1: per-nt MFMA + fused epilogue store
        {
            bf16x8 aw[15];
#pragma unroll
            for (int f2 = 0; f2 < 15; ++f2) {
                u32x4 t = *(const u32x4*)(pwl + (size_t)((f2 * 2 + 1) * 4 + wid) * 512);
                aw[f2] = __builtin_bit_cast(bf16x8, t);
            }
            const uint8_t* lb = lds + 4 * CGS + bbase;
#pragma unroll
            for (int nt = 0; nt < 4; ++nt) {
                DO_MFMAS()
                const int row_e = 4 * nt + 2 * io;
                const uint32_t me = io ? RM[4 * nt + 2] : RM[4 * nt + 0];
                const uint32_t mo = io ? RM[4 * nt + 3] : RM[4 * nt + 1];
                const uint32_t be  = (me >> (2 * j)) & 1u;
                const uint32_t bo0 = (mo >> (2 * j)) & 1u;
                const uint32_t bo1 = (mo >> (2 * j + 1)) & 1u;
#pragma unroll
                for (int r = 0; r < 4; ++r) {
                    int o = ob + r;
                    float up = acc[0][nt][r] + bias0[r];
                    float lf = acc[1][nt][r] + bias1[r];
                    float rt = acc[2][nt][r] + bias2[r];
                    up = be  ? up : 0.f;
                    lf = bo0 ? lf : 0.f;
                    rt = bo1 ? rt : 0.f;
                    float up_o = __shfl_xor(up, 1);
                    float lf_o = __shfl_xor(lf, 1);
                    float rt_o = __shfl_xor(rt, 1);
                    f32x4 v;
                    v[0] = odd ? lf_o : up;
                    v[1] = odd ? rt_o : 0.f;
                    v[2] = odd ? lf   : up_o;
                    v[3] = odd ? rt   : 0.f;
                    float* p = out + (((size_t)b * 64 + o) * 256 + (row_e + odd) * 16 + 4 * (j >> 1));
                    __builtin_nontemporal_store(v, (f32x4*)p);
                }
            }
        }
#undef DO_MFMAS
#undef BRD
        if (it + 1 < nb) __syncthreads();   // LDS reads done before next iter's staging
    }
}

extern "C" void kernel_launch(void* const* d_in, const int* in_sizes, int n_in,
                              void* d_out, int out_size, void* d_ws, size_t ws_size,
                              hipStream_t stream) {
    const float* x  = (const float*)d_in[0];
    const float* wu = (const float*)d_in[1];
    const float* bu = (const float*)d_in[2];
    const float* wl = (const float*)d_in[3];
    const float* bl = (const float*)d_in[4];
    const float* wr = (const float*)d_in[5];
    const float* br = (const float*)d_in[6];
    float* out   = (float*)d_out;
    uint16_t* pw = (uint16_t*)d_ws;          // 245,760 B of packed bf16 weights

    int B = in_sizes[0] / 16384;             // 2048
    pack_w<<<(NFRAG + 255) / 256, 256, 0, stream>>>(wu, wl, wr, pw);
    kagome_main<<<GRID, 256, 0, stream>>>(x, pw, bu, bl, br, out, B);
}

// Round 11
// 82.087 us; speedup vs baseline: 1.0945x; 1.0945x over previous
//
#include <hip/hip_runtime.h>
#include <stdint.h>
#include <stddef.h>

typedef __attribute__((ext_vector_type(4))) float    f32x4;
typedef __attribute__((ext_vector_type(4))) uint32_t u32x4;
typedef __attribute__((ext_vector_type(8))) __bf16   bf16x8;

// Compact cgroup plane: odd-parity cols [row 0..17][col/2 0..8] (2592 B) then
// even-parity cols [evenrow/2 0..8][col/2 0..8] (1296 B) = 3888 B used.
// (Even-parity sites at odd rows are NEVER read: all even-dc taps have even dr.)
// CGS=3968: q*CGS mod 512 = {0,384,256,128} -> staggered bank phases.
// 8 * 3968 = 31744 B LDS -> 5 blocks/CU.
#define CGS   3968
#define EVENP 2592      // byte offset of even-parity subplane
#define NFRAG 15360     // 15 (dir,tap) * 2 kk * 4 mtile * 64 lanes

// tap (kr,kc) per f = dir*5+tap  (dir: 0=up,1=left,2=right)
__device__ __constant__ uint8_t TAPR[15] = {0,0,1,2,2, 1,2,2,2,3, 1,2,2,2,3};
__device__ __constant__ uint8_t TAPC[15] = {0,1,1,1,2, 1,0,1,2,1, 1,1,2,3,3};

// periodic-boundary copies on padded 18x18 (dst <- src), sources never destinations.
// Verified: every dst/src with even col has even row (lattice structure).
__device__ __constant__ uint8_t PDR[30] = {1,1,2,3,4,4,6,7,8,10,11,12,14,14,15,16,17,17,16,15,14,14,12,10,8,6,4,4,3,2};
__device__ __constant__ uint8_t PDC[30] = {3,5,7,9,10,11,13,13,14,15,15,16,15,16,15,14,13,11,9,7,6,5,3,2,1,0,0,1,1,2};
__device__ __constant__ uint8_t PSR[30] = {13,13,14,15,16,16,6,7,8,10,11,12,2,2,3,4,5,5,4,3,2,2,12,10,8,6,16,16,15,14};
__device__ __constant__ uint8_t PSC[30] = {15,5,7,9,10,11,1,1,2,3,3,4,3,4,3,2,1,11,9,7,6,5,15,14,13,12,12,13,13,14};

__device__ __forceinline__ uint32_t pk2(float a, float b) {
    return (uint32_t)__builtin_bit_cast(uint16_t, (__bf16)a)
         | ((uint32_t)__builtin_bit_cast(uint16_t, (__bf16)b) << 16);
}

// byte offset within a cgroup plane (caller guarantees r even when c even)
__device__ __forceinline__ int slotb(int r, int c) {
    return (c & 1) ? (r * 144 + (c >> 1) * 16)
                   : (EVENP + (r >> 1) * 144 + (c >> 1) * 16);
}

// ---------------- weight packing: A-fragment layout for mfma_f32_16x16x32_bf16 ----------------
__global__ __launch_bounds__(256) void pack_w(const float* __restrict__ wu,
                                              const float* __restrict__ wl,
                                              const float* __restrict__ wr,
                                              uint16_t* __restrict__ pw) {
    int fid = blockIdx.x * 256 + threadIdx.x;
    if (fid >= NFRAG) return;
    int lane = fid & 63;
    int mt   = (fid >> 6) & 3;
    int kk   = (fid >> 8) & 1;
    int td   = fid >> 9;                 // 0..14 = dir*5+tap
    const float* w = (td < 5) ? wu : (td < 10) ? wl : wr;
    int o  = mt * 16 + (lane & 15);
    int cb = kk * 32 + (lane >> 4) * 8;
    int kr = TAPR[td], kc = TAPC[td];
    const float* src = w + ((size_t)o * 64 + cb) * 16 + kr * 4 + kc;
    uint32_t d[4];
#pragma unroll
    for (int p = 0; p < 4; ++p)
        d[p] = pk2(src[(2 * p) * 16], src[(2 * p + 1) * 16]);
    u32x4 v = {d[0], d[1], d[2], d[3]};
    *(u32x4*)(pw + (size_t)fid * 8) = v;
}

__global__ __launch_bounds__(256, 5) void kagome_main(const float* __restrict__ x,
                                                      const uint16_t* __restrict__ pw,
                                                      const float* __restrict__ bu,
                                                      const float* __restrict__ bl,
                                                      const float* __restrict__ br,
                                                      float* __restrict__ out) {
    __shared__ __align__(16) uint8_t lds[8 * CGS];
    const int tid = threadIdx.x;
    const int b   = blockIdx.x;

    // compute lane decomposition (also for hoisted bias loads)
    const int l   = tid & 63;
    const int wid = tid >> 6;
    const int q   = l >> 4;        // k-quarter
    const int io  = (l >> 3) & 1;  // row-pair within n-tile
    const int j   = l & 7;         // conv output column

    const int ob = wid * 16 + q * 4;
    f32x4 bias0 = *(const f32x4*)(bu + ob);
    f32x4 bias1 = *(const f32x4*)(bl + ob);
    f32x4 bias2 = *(const f32x4*)(br + ob);

    // ---- phase 1a: stage interior as bf16 (skip even-col writes at odd padded rows) ----
    {
        const float* xb = x + (size_t)b * 16384;
#pragma unroll
        for (int i = 0; i < 2; ++i) {
            const int t    = i * 256 + tid;
            const int cg   = t >> 6;        // 0..7 (uniform per wave)
            const int quad = t & 63;
            const int r0   = quad >> 2;
            const int qc   = quad & 3;
            const int pr   = r0 + 1;        // padded row 1..16
            f32x4 v[8];
#pragma unroll
            for (int ch = 0; ch < 8; ++ch)
                v[ch] = *(const f32x4*)(xb + (cg * 8 + ch) * 256 + quad * 4);
            uint8_t* base = lds + cg * CGS;
#pragma unroll
            for (int e = 0; e < 4; ++e) {
                const int c = 4 * qc + e + 1;
                if ((c & 1) || !(pr & 1)) {     // even-col sites exist only at even rows
                    u32x4 w = {pk2(v[0][e], v[1][e]), pk2(v[2][e], v[3][e]),
                               pk2(v[4][e], v[5][e]), pk2(v[6][e], v[7][e])};
                    *(u32x4*)(base + slotb(pr, c)) = w;
                }
            }
        }
        // ---- phase 1b: zero the 51 readable border sites x 8 cgroups ----
        u32x4 z = {0, 0, 0, 0};
        for (int idx = tid; idx < 51 * 8; idx += 256) {
            int s = idx >> 3, cg = idx & 7;
            int r, c;
            if (s < 18)      { r = 0;  c = s; }                       // row 0, all cols
            else if (s < 27) { r = 17; c = 2 * (s - 18) + 1; }        // row 17, odd cols
            else if (s < 35) { r = 2 * (s - 27) + 2; c = 0; }         // col 0, even rows
            else             { r = s - 35 + 1; c = 17; }              // col 17, rows 1..16
            *(u32x4*)(lds + cg * CGS + slotb(r, c)) = z;
        }
    }
    __syncthreads();
    // ---- phase 2: periodic copies ----
    if (tid < 240) {
        int pair = tid >> 3, cg = tid & 7;
        u32x4 v = *(const u32x4*)(lds + cg * CGS + slotb(PSR[pair], PSC[pair]));
        *(u32x4*)(lds + cg * CGS + slotb(PDR[pair], PDC[pair])) = v;
    }
    __syncthreads();

    // ---- compute ----
    f32x4 acc[3][4];
#pragma unroll
    for (int d2 = 0; d2 < 3; ++d2)
#pragma unroll
        for (int n2 = 0; n2 < 4; ++n2) acc[d2][n2] = (f32x4){0.f, 0.f, 0.f, 0.f};

    const uint16_t* pwl = pw + (size_t)l * 8;

    constexpr uint32_t RM[16] = {0x0008, 0x003C, 0x00FC, 0x01FE, 0x07FF, 0x0FFF, 0x0FFF, 0x1FFE,
                                 0x3FFE, 0xBFFC, 0xBFFC, 0x7FF8, 0xFFF0, 0x3FC0, 0x3F80, 0x1E00};
    const int odd = j & 1;

    // per-lane LDS bases: odd-parity and even-parity subplanes
    // odd-dc tap (r = 4nt+2io+dr):   lb_o + (4nt+dr)*144 + (dc>>1)*16
    // even-dc tap (dr even):        lb_e + (2nt+dr/2)*144 + (dc>>1)*16
#define BRD(dr, dc) __builtin_bit_cast(bf16x8, ((dc) & 1)                                      \
        ? *(const u32x4*)(lb_o + (4 * nt + (dr)) * 144 + ((dc) >> 1) * 16)                     \
        : *(const u32x4*)(lb_e + (2 * nt + ((dr) >> 1)) * 144 + ((dc) >> 1) * 16))
#define DO_MFMAS()                                                                             \
            bf16x8 b00 = BRD(0, 0);                                                            \
            acc[0][nt] = __builtin_amdgcn_mfma_f32_16x16x32_bf16(aw[0], b00, acc[0][nt], 0, 0, 0); \
            bf16x8 b01 = BRD(0, 1);                                                            \
            acc[0][nt] = __builtin_amdgcn_mfma_f32_16x16x32_bf16(aw[1], b01, acc[0][nt], 0, 0, 0); \
            bf16x8 b11 = BRD(1, 1);                                                            \
            acc[0][nt] = __builtin_amdgcn_mfma_f32_16x16x32_bf16(aw[2],  b11, acc[0][nt], 0, 0, 0); \
            acc[1][nt] = __builtin_amdgcn_mfma_f32_16x16x32_bf16(aw[5],  b11, acc[1][nt], 0, 0, 0); \
            acc[2][nt] = __builtin_amdgcn_mfma_f32_16x16x32_bf16(aw[10], b11, acc[2][nt], 0, 0, 0); \
            bf16x8 b20 = BRD(2, 0);                                                            \
            acc[1][nt] = __builtin_amdgcn_mfma_f32_16x16x32_bf16(aw[6],  b20, acc[1][nt], 0, 0, 0); \
            bf16x8 b21 = BRD(2, 1);                                                            \
            acc[0][nt] = __builtin_amdgcn_mfma_f32_16x16x32_bf16(aw[3],  b21, acc[0][nt], 0, 0, 0); \
            acc[1][nt] = __builtin_amdgcn_mfma_f32_16x16x32_bf16(aw[7],  b21, acc[1][nt], 0, 0, 0); \
            acc[2][nt] = __builtin_amdgcn_mfma_f32_16x16x32_bf16(aw[11], b21, acc[2][nt], 0, 0, 0); \
            bf16x8 b22 = BRD(2, 2);                                                            \
            acc[0][nt] = __builtin_amdgcn_mfma_f32_16x16x32_bf16(aw[4],  b22, acc[0][nt], 0, 0, 0); \
            acc[1][nt] = __builtin_amdgcn_mfma_f32_16x16x32_bf16(aw[8],  b22, acc[1][nt], 0, 0, 0); \
            acc[2][nt] = __builtin_amdgcn_mfma_f32_16x16x32_bf16(aw[12], b22, acc[2][nt], 0, 0, 0); \
            bf16x8 b23 = BRD(2, 3);                                                            \
            acc[2][nt] = __builtin_amdgcn_mfma_f32_16x16x32_bf16(aw[13], b23, acc[2][nt], 0, 0, 0); \
            bf16x8 b31 = BRD(3, 1);                                                            \
            acc[1][nt] = __builtin_amdgcn_mfma_f32_16x16x32_bf16(aw[9],  b31, acc[1][nt], 0, 0, 0); \
            bf16x8 b33 = BRD(3, 3);                                                            \
            acc[2][nt] = __builtin_amdgcn_mfma_f32_16x16x32_bf16(aw[14], b33, acc[2][nt], 0, 0, 0);

    // kk = 0: pure MFMA
    {
        bf16x8 aw[15];
#pragma unroll
        for (int f2 = 0; f2 < 15; ++f2) {
            u32x4 t = *(const u32x4*)(pwl + (size_t)((f2 * 2 + 0) * 4 + wid) * 512);
            aw[f2] = __builtin_bit_cast(bf16x8, t);
        }
        const uint8_t* lb_o = lds + q * CGS + io * 288 + j * 16;
        const uint8_t* lb_e = lds + q * CGS + EVENP + io * 144 + j * 16;
#pragma unroll
        for (int nt = 0; nt < 4; ++nt) {
            DO_MFMAS()
        }
    }
    // kk = 1: per-nt MFMA + fused epilogue store
    {
        bf16x8 aw[15];
#pragma unroll
        for (int f2 = 0; f2 < 15; ++f2) {
            u32x4 t = *(const u32x4*)(pwl + (size_t)((f2 * 2 + 1) * 4 + wid) * 512);
            aw[f2] = __builtin_bit_cast(bf16x8, t);
        }
        const uint8_t* lb_o = lds + (4 + q) * CGS + io * 288 + j * 16;
        const uint8_t* lb_e = lds + (4 + q) * CGS + EVENP + io * 144 + j * 16;
#pragma unroll
        for (int nt = 0; nt < 4; ++nt) {
            DO_MFMAS()
            const int row_e = 4 * nt + 2 * io;
            const uint32_t me = io ? RM[4 * nt + 2] : RM[4 * nt + 0];
            const uint32_t mo = io ? RM[4 * nt + 3] : RM[4 * nt + 1];
            const uint32_t be  = (me >> (2 * j)) & 1u;
            const uint32_t bo0 = (mo >> (2 * j)) & 1u;
            const uint32_t bo1 = (mo >> (2 * j + 1)) & 1u;
#pragma unroll
            for (int r = 0; r < 4; ++r) {
                int o = ob + r;
                float up = acc[0][nt][r] + bias0[r];
                float lf = acc[1][nt][r] + bias1[r];
                float rt = acc[2][nt][r] + bias2[r];
                up = be  ? up : 0.f;
                lf = bo0 ? lf : 0.f;
                rt = bo1 ? rt : 0.f;
                float up_o = __shfl_xor(up, 1);
                float lf_o = __shfl_xor(lf, 1);
                float rt_o = __shfl_xor(rt, 1);
                f32x4 v;
                v[0] = odd ? lf_o : up;
                v[1] = odd ? rt_o : 0.f;
                v[2] = odd ? lf   : up_o;
                v[3] = odd ? rt   : 0.f;
                float* p = out + (((size_t)b * 64 + o) * 256 + (row_e + odd) * 16 + 4 * (j >> 1));
                __builtin_nontemporal_store(v, (f32x4*)p);
            }
        }
    }
#undef DO_MFMAS
#undef BRD
}

extern "C" void kernel_launch(void* const* d_in, const int* in_sizes, int n_in,
                              void* d_out, int out_size, void* d_ws, size_t ws_size,
                              hipStream_t stream) {
    const float* x  = (const float*)d_in[0];
    const float* wu = (const float*)d_in[1];
    const float* bu = (const float*)d_in[2];
    const float* wl = (const float*)d_in[3];
    const float* bl = (const float*)d_in[4];
    const float* wr = (const float*)d_in[5];
    const float* br = (const float*)d_in[6];
    float* out   = (float*)d_out;
    uint16_t* pw = (uint16_t*)d_ws;          // 245,760 B of packed bf16 weights

    int B = in_sizes[0] / 16384;             // 2048
    pack_w<<<(NFRAG + 255) / 256, 256, 0, stream>>>(wu, wl, wr, pw);
    kagome_main<<<B, 256, 0, stream>>>(x, pw, bu, bl, br, out);
}

// Round 13
// 75.881 us; speedup vs baseline: 1.1840x; 1.0818x over previous
//
#include <hip/hip_runtime.h>
#include <stdint.h>
#include <stddef.h>

typedef __attribute__((ext_vector_type(4))) float    f32x4;
typedef __attribute__((ext_vector_type(4))) uint32_t u32x4;
typedef __attribute__((ext_vector_type(8))) __bf16   bf16x8;

#define CGS   5248      // bytes per channel-group plane (R9 known-good)
#define NFRAG 15360     // 15 (dir,tap) * 2 kk * 4 mtile * 64 lanes

// tap (kr,kc) per f = dir*5+tap  (dir: 0=up,1=left,2=right)
__device__ __constant__ uint8_t TAPR[15] = {0,0,1,2,2, 1,2,2,2,3, 1,2,2,2,3};
__device__ __constant__ uint8_t TAPC[15] = {0,1,1,1,2, 1,0,1,2,1, 1,1,2,3,3};

__device__ __forceinline__ uint32_t pk2(float a, float b) {
    return (uint32_t)__builtin_bit_cast(uint16_t, (__bf16)a)
         | ((uint32_t)__builtin_bit_cast(uint16_t, (__bf16)b) << 16);
}

// ---------------- weight packing: A-fragment layout for mfma_f32_16x16x32_bf16 ----------------
__global__ __launch_bounds__(256) void pack_w(const float* __restrict__ wu,
                                              const float* __restrict__ wl,
                                              const float* __restrict__ wr,
                                              uint16_t* __restrict__ pw) {
    int fid = blockIdx.x * 256 + threadIdx.x;
    if (fid >= NFRAG) return;
    int lane = fid & 63;
    int mt   = (fid >> 6) & 3;
    int kk   = (fid >> 8) & 1;
    int td   = fid >> 9;                 // 0..14 = dir*5+tap
    const float* w = (td < 5) ? wu : (td < 10) ? wl : wr;
    int o  = mt * 16 + (lane & 15);
    int cb = kk * 32 + (lane >> 4) * 8;
    int kr = TAPR[td], kc = TAPC[td];
    const float* src = w + ((size_t)o * 64 + cb) * 16 + kr * 4 + kc;
    uint32_t d[4];
#pragma unroll
    for (int p = 0; p < 4; ++p)
        d[p] = pk2(src[(2 * p) * 16], src[(2 * p + 1) * 16]);
    u32x4 v = {d[0], d[1], d[2], d[3]};
    *(u32x4*)(pw + (size_t)fid * 8) = v;
}

// slot within a channel-group plane, column-parity split: 16 B per slot (8 channels, one pixel)
__device__ __forceinline__ int slotof(int r, int c) { return (c & 1) * 162 + r * 9 + (c >> 1); }

// Fused periodic copies: copy c's dst value = x[src pixel]; the staging thread that owns
// the src pixel (quad SRCQ, element SRCE) writes it straight to dst slot DSLOT.
// SKIPM[e] bit q: interior staging write (quad q, elem e) is a copy dst -> dead, skip it.
__constant__ uint8_t SRCQ[30] = {51,49,53,58,62,62,20,24,28,36,40,44,4,4,8,12,16,18,14,9,5,5,47,39,31,22,62,63,59,55};
__constant__ uint8_t SRCE[30] = {2,0,2,0,1,2,0,0,1,2,2,3,2,3,2,1,0,2,0,2,1,0,2,1,0,3,3,0,0,1};
__constant__ uint16_t DSLOT[30] = {172,173,183,193,41,203,222,231,79,259,268,116,295,134,304,151,321,320,310,300,129,290,271,91,234,54,36,198,189,19};

__global__ __launch_bounds__(256, 3) void kagome_main(const float* __restrict__ x,
                                                      const uint16_t* __restrict__ pw,
                                                      const float* __restrict__ bu,
                                                      const float* __restrict__ bl,
                                                      const float* __restrict__ br,
                                                      float* __restrict__ out) {
    __shared__ __align__(16) uint8_t lds[8 * CGS];
    const int tid = threadIdx.x;
    const int b   = blockIdx.x;

    // compute lane decomposition (also for hoisted bias loads)
    const int l   = tid & 63;
    const int wid = tid >> 6;
    const int q   = l >> 4;        // k-quarter
    const int io  = (l >> 3) & 1;  // row-pair within n-tile
    const int j   = l & 7;         // conv output column

    const int ob = wid * 16 + q * 4;
    f32x4 bias0 = *(const f32x4*)(bu + ob);
    f32x4 bias1 = *(const f32x4*)(bl + ob);
    f32x4 bias2 = *(const f32x4*)(br + ob);

    // interior-dst skip masks, bit = quad, per element e
    // e0: quads {1,8,10,12,23,27,28,53,62}; e1: {4,14,31,36,53,63};
    // e2: {0,5,14,39,43,44,55,57,59};      e3: {47,55}
    constexpr uint64_t SKIPM[4] = {0x4020000018801502ull, 0x8020001080004010ull,
                                   0x0A80188000004021ull, 0x0080800000000000ull};

    // ---- phase 1: stage interior + zero borders + FUSED periodic copies (one barrier) ----
    {
        const float* xb = x + (size_t)b * 16384;
        const int quad = tid & 63;
        const int r0   = quad >> 2;
        const int qc   = quad & 3;
#pragma unroll
        for (int i = 0; i < 2; ++i) {
            const int cg = (tid >> 6) + 4 * i;
            f32x4 v[8];
#pragma unroll
            for (int ch = 0; ch < 8; ++ch)
                v[ch] = *(const f32x4*)(xb + (cg * 8 + ch) * 256 + quad * 4);
            uint8_t* base = lds + cg * CGS;
#pragma unroll
            for (int e = 0; e < 4; ++e) {
                if (!((SKIPM[e] >> quad) & 1ull)) {
                    u32x4 w = {pk2(v[0][e], v[1][e]), pk2(v[2][e], v[3][e]),
                               pk2(v[4][e], v[5][e]), pk2(v[6][e], v[7][e])};
                    *(u32x4*)(base + slotof(r0 + 1, 4 * qc + e + 1) * 16) = w;
                }
            }
            // fused copies: this thread owns src pixels of some copies -> write dst slots
#pragma unroll
            for (int c2 = 0; c2 < 30; ++c2) {
                if (quad == SRCQ[c2]) {
                    const int e = SRCE[c2];
                    u32x4 w = {pk2(v[0][e], v[1][e]), pk2(v[2][e], v[3][e]),
                               pk2(v[4][e], v[5][e]), pk2(v[6][e], v[7][e])};
                    *(u32x4*)(base + (int)DSLOT[c2] * 16) = w;
                }
            }
        }
        // zero border sites EXCEPT the 4 copy-dst border sites (s = 29,31,42,46)
        u32x4 z = {0, 0, 0, 0};
        for (int idx = tid; idx < 68 * 8; idx += 256) {
            int s = idx >> 3, cg = idx & 7;
            if (s == 29 || s == 31 || s == 42 || s == 46) continue;
            int r, c;
            if (s < 18)      { r = 0;  c = s; }
            else if (s < 36) { r = 17; c = s - 18; }
            else             { int k2 = s - 36; r = 1 + (k2 >> 1); c = (k2 & 1) * 17; }
            *(u32x4*)(lds + cg * CGS + slotof(r, c) * 16) = z;
        }
    }
    __syncthreads();

    // ---- compute ----
    f32x4 acc[3][4];
#pragma unroll
    for (int d2 = 0; d2 < 3; ++d2)
#pragma unroll
        for (int n2 = 0; n2 < 4; ++n2) acc[d2][n2] = (f32x4){0.f, 0.f, 0.f, 0.f};

    const int bbase = q * CGS + io * 288 + j * 16;
    const uint16_t* pwl = pw + (size_t)l * 8;

    constexpr uint32_t RM[16] = {0x0008, 0x003C, 0x00FC, 0x01FE, 0x07FF, 0x0FFF, 0x0FFF, 0x1FFE,
                                 0x3FFE, 0xBFFC, 0xBFFC, 0x7FF8, 0xFFF0, 0x3FC0, 0x3F80, 0x1E00};
    const int odd = j & 1;

#define BRD(dr, dc) __builtin_bit_cast(bf16x8, *(const u32x4*)(lb + ((dc) & 1) * 2592 + (4 * nt + (dr)) * 144 + ((dc) >> 1) * 16))
#define DO_MFMAS()                                                                             \
            bf16x8 b00 = BRD(0, 0);                                                            \
            acc[0][nt] = __builtin_amdgcn_mfma_f32_16x16x32_bf16(aw[0], b00, acc[0][nt], 0, 0, 0); \
            bf16x8 b01 = BRD(0, 1);                                                            \
            acc[0][nt] = __builtin_amdgcn_mfma_f32_16x16x32_bf16(aw[1], b01, acc[0][nt], 0, 0, 0); \
            bf16x8 b11 = BRD(1, 1);                                                            \
            acc[0][nt] = __builtin_amdgcn_mfma_f32_16x16x32_bf16(aw[2],  b11, acc[0][nt], 0, 0, 0); \
            acc[1][nt] = __builtin_amdgcn_mfma_f32_16x16x32_bf16(aw[5],  b11, acc[1][nt], 0, 0, 0); \
            acc[2][nt] = __builtin_amdgcn_mfma_f32_16x16x32_bf16(aw[10], b11, acc[2][nt], 0, 0, 0); \
            bf16x8 b20 = BRD(2, 0);                                                            \
            acc[1][nt] = __builtin_amdgcn_mfma_f32_16x16x32_bf16(aw[6],  b20, acc[1][nt], 0, 0, 0); \
            bf16x8 b21 = BRD(2, 1);                                                            \
            acc[0][nt] = __builtin_amdgcn_mfma_f32_16x16x32_bf16(aw[3],  b21, acc[0][nt], 0, 0, 0); \
            acc[1][nt] = __builtin_amdgcn_mfma_f32_16x16x32_bf16(aw[7],  b21, acc[1][nt], 0, 0, 0); \
            acc[2][nt] = __builtin_amdgcn_mfma_f32_16x16x32_bf16(aw[11], b21, acc[2][nt], 0, 0, 0); \
            bf16x8 b22 = BRD(2, 2);                                                            \
            acc[0][nt] = __builtin_amdgcn_mfma_f32_16x16x32_bf16(aw[4],  b22, acc[0][nt], 0, 0, 0); \
            acc[1][nt] = __builtin_amdgcn_mfma_f32_16x16x32_bf16(aw[8],  b22, acc[1][nt], 0, 0, 0); \
            acc[2][nt] = __builtin_amdgcn_mfma_f32_16x16x32_bf16(aw[12], b22, acc[2][nt], 0, 0, 0); \
            bf16x8 b23 = BRD(2, 3);                                                            \
            acc[2][nt] = __builtin_amdgcn_mfma_f32_16x16x32_bf16(aw[13], b23, acc[2][nt], 0, 0, 0); \
            bf16x8 b31 = BRD(3, 1);                                                            \
            acc[1][nt] = __builtin_amdgcn_mfma_f32_16x16x32_bf16(aw[9],  b31, acc[1][nt], 0, 0, 0); \
            bf16x8 b33 = BRD(3, 3);                                                            \
            acc[2][nt] = __builtin_amdgcn_mfma_f32_16x16x32_bf16(aw[14], b33, acc[2][nt], 0, 0, 0);

    // kk = 0: pure MFMA
    {
        bf16x8 aw[15];
#pragma unroll
        for (int f2 = 0; f2 < 15; ++f2) {
            u32x4 t = *(const u32x4*)(pwl + (size_t)((f2 * 2 + 0) * 4 + wid) * 512);
            aw[f2] = __builtin_bit_cast(bf16x8, t);
        }
        const uint8_t* lb = lds + bbase;
#pragma unroll
        for (int nt = 0; nt < 4; ++nt) {
            DO_MFMAS()
        }
    }
    // kk = 1: per-nt MFMA + fused epilogue store
    {
        bf16x8 aw[15];
#pragma unroll
        for (int f2 = 0; f2 < 15; ++f2) {
            u32x4 t = *(const u32x4*)(pwl + (size_t)((f2 * 2 + 1) * 4 + wid) * 512);
            aw[f2] = __builtin_bit_cast(bf16x8, t);
        }
        const uint8_t* lb = lds + 4 * CGS + bbase;
#pragma unroll
        for (int nt = 0; nt < 4; ++nt) {
            DO_MFMAS()
            const int row_e = 4 * nt + 2 * io;
            const uint32_t me = io ? RM[4 * nt + 2] : RM[4 * nt + 0];
            const uint32_t mo = io ? RM[4 * nt + 3] : RM[4 * nt + 1];
            const uint32_t be  = (me >> (2 * j)) & 1u;
            const uint32_t bo0 = (mo >> (2 * j)) & 1u;
            const uint32_t bo1 = (mo >> (2 * j + 1)) & 1u;
#pragma unroll
            for (int r = 0; r < 4; ++r) {
                int o = ob + r;
                float up = acc[0][nt][r] + bias0[r];
                float lf = acc[1][nt][r] + bias1[r];
                float rt = acc[2][nt][r] + bias2[r];
                up = be  ? up : 0.f;
                lf = bo0 ? lf : 0.f;
                rt = bo1 ? rt : 0.f;
                float up_o = __shfl_xor(up, 1);
                float lf_o = __shfl_xor(lf, 1);
                float rt_o = __shfl_xor(rt, 1);
                f32x4 v;
                v[0] = odd ? lf_o : up;
                v[1] = odd ? rt_o : 0.f;
                v[2] = odd ? lf   : up_o;
                v[3] = odd ? rt   : 0.f;
                float* p = out + (((size_t)b * 64 + o) * 256 + (row_e + odd) * 16 + 4 * (j >> 1));
                __builtin_nontemporal_store(v, (f32x4*)p);
            }
        }
    }
#undef DO_MFMAS
#undef BRD
}

extern "C" void kernel_launch(void* const* d_in, const int* in_sizes, int n_in,
                              void* d_out, int out_size, void* d_ws, size_t ws_size,
                              hipStream_t stream) {
    const float* x  = (const float*)d_in[0];
    const float* wu = (const float*)d_in[1];
    const float* bu = (const float*)d_in[2];
    const float* wl = (const float*)d_in[3];
    const float* bl = (const float*)d_in[4];
    const float* wr = (const float*)d_in[5];
    const float* br = (const float*)d_in[6];
    float* out   = (float*)d_out;
    uint16_t* pw = (uint16_t*)d_ws;          // 245,760 B of packed bf16 weights

    int B = in_sizes[0] / 16384;             // 2048
    pack_w<<<(NFRAG + 255) / 256, 256, 0, stream>>>(wu, wl, wr, pw);
    kagome_main<<<B, 256, 0, stream>>>(x, pw, bu, bl, br, out);
}

// Round 14
// 62.348 us; speedup vs baseline: 1.4410x; 1.2171x over previous
//
#include <hip/hip_runtime.h>
#include <stdint.h>
#include <stddef.h>

typedef __attribute__((ext_vector_type(4))) float    f32x4;
typedef __attribute__((ext_vector_type(4))) uint32_t u32x4;
typedef __attribute__((ext_vector_type(8))) __bf16   bf16x8;

#define CGS   5248      // bytes per channel-group plane (R9 known-good)
#define NFRAG 15360     // 15 (dir,tap) * 2 kk * 4 mtile * 64 lanes

// tap (kr,kc) per f = dir*5+tap  (dir: 0=up,1=left,2=right)
__device__ __constant__ uint8_t TAPR[15] = {0,0,1,2,2, 1,2,2,2,3, 1,2,2,2,3};
__device__ __constant__ uint8_t TAPC[15] = {0,1,1,1,2, 1,0,1,2,1, 1,1,2,3,3};

__device__ __forceinline__ uint32_t pk2(float a, float b) {
    return (uint32_t)__builtin_bit_cast(uint16_t, (__bf16)a)
         | ((uint32_t)__builtin_bit_cast(uint16_t, (__bf16)b) << 16);
}

// ---------------- weight packing: A-fragment layout for mfma_f32_16x16x32_bf16 ----------------
__global__ __launch_bounds__(256) void pack_w(const float* __restrict__ wu,
                                              const float* __restrict__ wl,
                                              const float* __restrict__ wr,
                                              uint16_t* __restrict__ pw) {
    int fid = blockIdx.x * 256 + threadIdx.x;
    if (fid >= NFRAG) return;
    int lane = fid & 63;
    int mt   = (fid >> 6) & 3;
    int kk   = (fid >> 8) & 1;
    int td   = fid >> 9;                 // 0..14 = dir*5+tap
    const float* w = (td < 5) ? wu : (td < 10) ? wl : wr;
    int o  = mt * 16 + (lane & 15);
    int cb = kk * 32 + (lane >> 4) * 8;
    int kr = TAPR[td], kc = TAPC[td];
    const float* src = w + ((size_t)o * 64 + cb) * 16 + kr * 4 + kc;
    uint32_t d[4];
#pragma unroll
    for (int p = 0; p < 4; ++p)
        d[p] = pk2(src[(2 * p) * 16], src[(2 * p + 1) * 16]);
    u32x4 v = {d[0], d[1], d[2], d[3]};
    *(u32x4*)(pw + (size_t)fid * 8) = v;
}

// slot within a channel-group plane, column-parity split: 16 B per slot (8 channels, one pixel)
__device__ __forceinline__ int slotof(int r, int c) { return (c & 1) * 162 + r * 9 + (c >> 1); }

// Fused periodic copies, O(1) per thread:
// COPYM[e] bit q: staging thread (quad q, elem e) is the SOURCE of a copy; it also
// writes its pk2 vector to dst slot DTAB[e][q]. Sources are never destinations, so
// the same w feeds both the main write and the copy write; each slot has one writer.
// SKIPM[e] bit q: interior site (q,e) is a copy dst -> its staging write is dead.
__constant__ uint16_t DTAB[4][64] = {
  {0,0,0,0,0,290,0,0,0,0,0,0,0,0,310,0, 321,0,0,0,222,0,0,0,231,0,0,0,0,0,0,234,
   0,0,0,0,0,0,0,0,0,0,0,0,0,0,0,0, 0,173,0,0,0,0,0,0,0,0,193,189,0,0,0,198},
  {0,0,0,0,0,129,0,0,0,0,0,0,151,0,0,0, 0,0,0,0,0,0,0,0,0,0,0,0,79,0,0,0,
   0,0,0,0,0,0,0,91,0,0,0,0,0,0,0,0, 0,0,0,0,0,0,0,19,0,0,0,0,0,0,41,0},
  {0,0,0,0,295,0,0,0,304,300,0,0,0,0,0,0, 0,0,320,0,0,0,0,0,0,0,0,0,0,0,0,0,
   0,0,0,0,259,0,0,0,268,0,0,0,0,0,0,271, 0,0,0,172,0,183,0,0,0,0,0,0,0,0,203,0},
  {0,0,0,0,134,0,0,0,0,0,0,0,0,0,0,0, 0,0,0,0,0,0,54,0,0,0,0,0,0,0,0,0,
   0,0,0,0,0,0,0,0,0,0,0,0,116,0,0,0, 0,0,0,0,0,0,0,0,0,0,0,0,0,0,36,0}};

__global__ __launch_bounds__(256, 3) void kagome_main(const float* __restrict__ x,
                                                      const uint16_t* __restrict__ pw,
                                                      const float* __restrict__ bu,
                                                      const float* __restrict__ bl,
                                                      const float* __restrict__ br,
                                                      float* __restrict__ out) {
    __shared__ __align__(16) uint8_t lds[8 * CGS];
    const int tid = threadIdx.x;
    const int b   = blockIdx.x;

    // compute lane decomposition (also for hoisted bias loads)
    const int l   = tid & 63;
    const int wid = tid >> 6;
    const int q   = l >> 4;        // k-quarter
    const int io  = (l >> 3) & 1;  // row-pair within n-tile
    const int j   = l & 7;         // conv output column

    const int ob = wid * 16 + q * 4;
    f32x4 bias0 = *(const f32x4*)(bu + ob);
    f32x4 bias1 = *(const f32x4*)(bl + ob);
    f32x4 bias2 = *(const f32x4*)(br + ob);

    // skip (copy-dst) and copy-src masks, bit = quad, per element e (verified R13-pass)
    constexpr uint64_t SKIPM[4] = {0x4020000018801502ull, 0x8020001080004010ull,
                                   0x0A80188000004021ull, 0x0080800000000000ull};
    constexpr uint64_t COPYM[4] = {0x8C02000081114020ull, 0x4080008010001020ull,
                                   0x4028811000040310ull, 0x4000100000400010ull};

    // ---- phase 1: stage interior + zero borders + fused periodic copies (one barrier) ----
    {
        const float* xb = x + (size_t)b * 16384;
        const int quad = tid & 63;
        const int r0   = quad >> 2;
        const int qc   = quad & 3;
#pragma unroll
        for (int i = 0; i < 2; ++i) {
            const int cg = (tid >> 6) + 4 * i;
            f32x4 v[8];
#pragma unroll
            for (int ch = 0; ch < 8; ++ch)
                v[ch] = *(const f32x4*)(xb + (cg * 8 + ch) * 256 + quad * 4);
            uint8_t* base = lds + cg * CGS;
#pragma unroll
            for (int e = 0; e < 4; ++e) {
                u32x4 w = {pk2(v[0][e], v[1][e]), pk2(v[2][e], v[3][e]),
                           pk2(v[4][e], v[5][e]), pk2(v[6][e], v[7][e])};
                if (!((SKIPM[e] >> quad) & 1ull))
                    *(u32x4*)(base + slotof(r0 + 1, 4 * qc + e + 1) * 16) = w;
                if ((COPYM[e] >> quad) & 1ull)
                    *(u32x4*)(base + (int)DTAB[e][quad] * 16) = w;
            }
        }
        // zero border sites EXCEPT the 4 copy-dst border sites (s = 29,31,42,46)
        u32x4 z = {0, 0, 0, 0};
        for (int idx = tid; idx < 68 * 8; idx += 256) {
            int s = idx >> 3, cg = idx & 7;
            if (s == 29 || s == 31 || s == 42 || s == 46) continue;
            int r, c;
            if (s < 18)      { r = 0;  c = s; }
            else if (s < 36) { r = 17; c = s - 18; }
            else             { int k2 = s - 36; r = 1 + (k2 >> 1); c = (k2 & 1) * 17; }
            *(u32x4*)(lds + cg * CGS + slotof(r, c) * 16) = z;
        }
    }
    __syncthreads();

    // ---- compute ----
    f32x4 acc[3][4];
#pragma unroll
    for (int d2 = 0; d2 < 3; ++d2)
#pragma unroll
        for (int n2 = 0; n2 < 4; ++n2) acc[d2][n2] = (f32x4){0.f, 0.f, 0.f, 0.f};

    const int bbase = q * CGS + io * 288 + j * 16;
    const uint16_t* pwl = pw + (size_t)l * 8;

    constexpr uint32_t RM[16] = {0x0008, 0x003C, 0x00FC, 0x01FE, 0x07FF, 0x0FFF, 0x0FFF, 0x1FFE,
                                 0x3FFE, 0xBFFC, 0xBFFC, 0x7FF8, 0xFFF0, 0x3FC0, 0x3F80, 0x1E00};
    const int odd = j & 1;

#define BRD(dr, dc) __builtin_bit_cast(bf16x8, *(const u32x4*)(lb + ((dc) & 1) * 2592 + (4 * nt + (dr)) * 144 + ((dc) >> 1) * 16))
#define DO_MFMAS()                                                                             \
            bf16x8 b00 = BRD(0, 0);                                                            \
            acc[0][nt] = __builtin_amdgcn_mfma_f32_16x16x32_bf16(aw[0], b00, acc[0][nt], 0, 0, 0); \
            bf16x8 b01 = BRD(0, 1);                                                            \
            acc[0][nt] = __builtin_amdgcn_mfma_f32_16x16x32_bf16(aw[1], b01, acc[0][nt], 0, 0, 0); \
            bf16x8 b11 = BRD(1, 1);                                                            \
            acc[0][nt] = __builtin_amdgcn_mfma_f32_16x16x32_bf16(aw[2],  b11, acc[0][nt], 0, 0, 0); \
            acc[1][nt] = __builtin_amdgcn_mfma_f32_16x16x32_bf16(aw[5],  b11, acc[1][nt], 0, 0, 0); \
            acc[2][nt] = __builtin_amdgcn_mfma_f32_16x16x32_bf16(aw[10], b11, acc[2][nt], 0, 0, 0); \
            bf16x8 b20 = BRD(2, 0);                                                            \
            acc[1][nt] = __builtin_amdgcn_mfma_f32_16x16x32_bf16(aw[6],  b20, acc[1][nt], 0, 0, 0); \
            bf16x8 b21 = BRD(2, 1);                                                            \
            acc[0][nt] = __builtin_amdgcn_mfma_f32_16x16x32_bf16(aw[3],  b21, acc[0][nt], 0, 0, 0); \
            acc[1][nt] = __builtin_amdgcn_mfma_f32_16x16x32_bf16(aw[7],  b21, acc[1][nt], 0, 0, 0); \
            acc[2][nt] = __builtin_amdgcn_mfma_f32_16x16x32_bf16(aw[11], b21, acc[2][nt], 0, 0, 0); \
            bf16x8 b22 = BRD(2, 2);                                                            \
            acc[0][nt] = __builtin_amdgcn_mfma_f32_16x16x32_bf16(aw[4],  b22, acc[0][nt], 0, 0, 0); \
            acc[1][nt] = __builtin_amdgcn_mfma_f32_16x16x32_bf16(aw[8],  b22, acc[1][nt], 0, 0, 0); \
            acc[2][nt] = __builtin_amdgcn_mfma_f32_16x16x32_bf16(aw[12], b22, acc[2][nt], 0, 0, 0); \
            bf16x8 b23 = BRD(2, 3);                                                            \
            acc[2][nt] = __builtin_amdgcn_mfma_f32_16x16x32_bf16(aw[13], b23, acc[2][nt], 0, 0, 0); \
            bf16x8 b31 = BRD(3, 1);                                                            \
            acc[1][nt] = __builtin_amdgcn_mfma_f32_16x16x32_bf16(aw[9],  b31, acc[1][nt], 0, 0, 0); \
            bf16x8 b33 = BRD(3, 3);                                                            \
            acc[2][nt] = __builtin_amdgcn_mfma_f32_16x16x32_bf16(aw[14], b33, acc[2][nt], 0, 0, 0);

    // kk = 0: pure MFMA
    {
        bf16x8 aw[15];
#pragma unroll
        for (int f2 = 0; f2 < 15; ++f2) {
            u32x4 t = *(const u32x4*)(pwl + (size_t)((f2 * 2 + 0) * 4 + wid) * 512);
            aw[f2] = __builtin_bit_cast(bf16x8, t);
        }
        const uint8_t* lb = lds + bbase;
#pragma unroll
        for (int nt = 0; nt < 4; ++nt) {
            DO_MFMAS()
        }
    }
    // kk = 1: per-nt MFMA + fused epilogue store
    {
        bf16x8 aw[15];
#pragma unroll
        for (int f2 = 0; f2 < 15; ++f2) {
            u32x4 t = *(const u32x4*)(pwl + (size_t)((f2 * 2 + 1) * 4 + wid) * 512);
            aw[f2] = __builtin_bit_cast(bf16x8, t);
        }
        const uint8_t* lb = lds + 4 * CGS + bbase;
#pragma unroll
        for (int nt = 0; nt < 4; ++nt) {
            DO_MFMAS()
            const int row_e = 4 * nt + 2 * io;
            const uint32_t me = io ? RM[4 * nt + 2] : RM[4 * nt + 0];
            const uint32_t mo = io ? RM[4 * nt + 3] : RM[4 * nt + 1];
            const uint32_t be  = (me >> (2 * j)) & 1u;
            const uint32_t bo0 = (mo >> (2 * j)) & 1u;
            const uint32_t bo1 = (mo >> (2 * j + 1)) & 1u;
#pragma unroll
            for (int r = 0; r < 4; ++r) {
                int o = ob + r;
                float up = acc[0][nt][r] + bias0[r];
                float lf = acc[1][nt][r] + bias1[r];
                float rt = acc[2][nt][r] + bias2[r];
                up = be  ? up : 0.f;
                lf = bo0 ? lf : 0.f;
                rt = bo1 ? rt : 0.f;
                float up_o = __shfl_xor(up, 1);
                float lf_o = __shfl_xor(lf, 1);
                float rt_o = __shfl_xor(rt, 1);
                f32x4 v;
                v[0] = odd ? lf_o : up;
                v[1] = odd ? rt_o : 0.f;
                v[2] = odd ? lf   : up_o;
                v[3] = odd ? rt   : 0.f;
                float* p = out + (((size_t)b * 64 + o) * 256 + (row_e + odd) * 16 + 4 * (j >> 1));
                __builtin_nontemporal_store(v, (f32x4*)p);
            }
        }
    }
#undef DO_MFMAS
#undef BRD
}

extern "C" void kernel_launch(void* const* d_in, const int* in_sizes, int n_in,
                              void* d_out, int out_size, void* d_ws, size_t ws_size,
                              hipStream_t stream) {
    const float* x  = (const float*)d_in[0];
    const float* wu = (const float*)d_in[1];
    const float* bu = (const float*)d_in[2];
    const float* wl = (const float*)d_in[3];
    const float* bl = (const float*)d_in[4];
    const float* wr = (const float*)d_in[5];
    const float* br = (const float*)d_in[6];
    float* out   = (float*)d_out;
    uint16_t* pw = (uint16_t*)d_ws;          // 245,760 B of packed bf16 weights

    int B = in_sizes[0] / 16384;             // 2048
    pack_w<<<(NFRAG + 255) / 256, 256, 0, stream>>>(wu, wl, wr, pw);
    kagome_main<<<B, 256, 0, stream>>>(x, pw, bu, bl, br, out);
}

// Round 15
// 56.835 us; speedup vs baseline: 1.5808x; 1.0970x over previous
//
#include <hip/hip_runtime.h>
#include <stdint.h>
#include <stddef.h>

typedef __attribute__((ext_vector_type(4))) float    f32x4;
typedef __attribute__((ext_vector_type(4))) uint32_t u32x4;
typedef __attribute__((ext_vector_type(8))) __bf16   bf16x8;

#define CGS   5200      // bytes per channel-group plane (best-measured config, R9 = 57.0 us)
#define NFRAG 15360     // 15 (dir,tap) * 2 kk * 4 mtile * 64 lanes

// tap (kr,kc) per f = dir*5+tap  (dir: 0=up,1=left,2=right)
__device__ __constant__ uint8_t TAPR[15] = {0,0,1,2,2, 1,2,2,2,3, 1,2,2,2,3};
__device__ __constant__ uint8_t TAPC[15] = {0,1,1,1,2, 1,0,1,2,1, 1,1,2,3,3};

// periodic-boundary copies on padded 18x18 (dst <- src), sources never destinations
__device__ __constant__ uint8_t PDR[30] = {1,1,2,3,4,4,6,7,8,10,11,12,14,14,15,16,17,17,16,15,14,14,12,10,8,6,4,4,3,2};
__device__ __constant__ uint8_t PDC[30] = {3,5,7,9,10,11,13,13,14,15,15,16,15,16,15,14,13,11,9,7,6,5,3,2,1,0,0,1,1,2};
__device__ __constant__ uint8_t PSR[30] = {13,13,14,15,16,16,6,7,8,10,11,12,2,2,3,4,5,5,4,3,2,2,12,10,8,6,16,16,15,14};
__device__ __constant__ uint8_t PSC[30] = {15,5,7,9,10,11,1,1,2,3,3,4,3,4,3,2,1,11,9,7,6,5,15,14,13,12,12,13,13,14};

__device__ __forceinline__ uint32_t pk2(float a, float b) {
    return (uint32_t)__builtin_bit_cast(uint16_t, (__bf16)a)
         | ((uint32_t)__builtin_bit_cast(uint16_t, (__bf16)b) << 16);
}

// ---------------- weight packing: A-fragment layout for mfma_f32_16x16x32_bf16 ----------------
__global__ __launch_bounds__(256) void pack_w(const float* __restrict__ wu,
                                              const float* __restrict__ wl,
                                              const float* __restrict__ wr,
                                              uint16_t* __restrict__ pw) {
    int fid = blockIdx.x * 256 + threadIdx.x;
    if (fid >= NFRAG) return;
    int lane = fid & 63;
    int mt   = (fid >> 6) & 3;
    int kk   = (fid >> 8) & 1;
    int td   = fid >> 9;                 // 0..14 = dir*5+tap
    const float* w = (td < 5) ? wu : (td < 10) ? wl : wr;
    int o  = mt * 16 + (lane & 15);
    int cb = kk * 32 + (lane >> 4) * 8;
    int kr = TAPR[td], kc = TAPC[td];
    const float* src = w + ((size_t)o * 64 + cb) * 16 + kr * 4 + kc;
    uint32_t d[4];
#pragma unroll
    for (int p = 0; p < 4; ++p)
        d[p] = pk2(src[(2 * p) * 16], src[(2 * p + 1) * 16]);
    u32x4 v = {d[0], d[1], d[2], d[3]};
    *(u32x4*)(pw + (size_t)fid * 8) = v;
}

// slot within a channel-group plane, column-parity split: 16 B per slot (8 channels, one pixel)
__device__ __forceinline__ int slotof(int r, int c) { return (c & 1) * 162 + r * 9 + (c >> 1); }

__global__ __launch_bounds__(256, 3) void kagome_main(const float* __restrict__ x,
                                                      const uint16_t* __restrict__ pw,
                                                      const float* __restrict__ bu,
                                                      const float* __restrict__ bl,
                                                      const float* __restrict__ br,
                                                      float* __restrict__ out) {
    __shared__ __align__(16) uint8_t lds[8 * CGS];
    const int tid = threadIdx.x;
    const int b   = blockIdx.x;

    // compute lane decomposition (also used for hoisted bias loads)
    const int l   = tid & 63;
    const int wid = tid >> 6;
    const int q   = l >> 4;        // k-quarter
    const int io  = (l >> 3) & 1;  // row-pair within n-tile
    const int j   = l & 7;         // conv output column

    // hoisted bias loads: one dwordx4 per direction
    const int ob = wid * 16 + q * 4;
    f32x4 bias0 = *(const f32x4*)(bu + ob);
    f32x4 bias1 = *(const f32x4*)(bl + ob);
    f32x4 bias2 = *(const f32x4*)(br + ob);

    // ---- phase 1a: stage interior (16x16) as bf16. Task = (channel-group, pixel-quad).
    {
        const float* xb = x + (size_t)b * 16384;
#pragma unroll
        for (int i = 0; i < 2; ++i) {
            const int t    = i * 256 + tid;
            const int cg   = t >> 6;        // 0..7 (uniform per wave)
            const int quad = t & 63;        // row r0 = quad>>2, cols 4*(quad&3)..+3
            const int r0   = quad >> 2;
            const int qc   = quad & 3;
            f32x4 v[8];
#pragma unroll
            for (int ch = 0; ch < 8; ++ch)
                v[ch] = *(const f32x4*)(xb + (cg * 8 + ch) * 256 + quad * 4);
            uint8_t* base = lds + cg * CGS;
#pragma unroll
            for (int e = 0; e < 4; ++e) {
                const int pc   = 4 * qc + e + 1;              // padded col
                const int slot = slotof(r0 + 1, pc);
                u32x4 w = {pk2(v[0][e], v[1][e]), pk2(v[2][e], v[3][e]),
                           pk2(v[4][e], v[5][e]), pk2(v[6][e], v[7][e])};
                *(u32x4*)(base + slot * 16) = w;
            }
        }
        // ---- phase 1b: zero all 68 border sites (disjoint from interior) ----
        u32x4 z = {0, 0, 0, 0};
        for (int idx = tid; idx < 68 * 8; idx += 256) {
            int s = idx >> 3, cg = idx & 7;
            int r, c;
            if (s < 18)      { r = 0;  c = s; }
            else if (s < 36) { r = 17; c = s - 18; }
            else             { int k2 = s - 36; r = 1 + (k2 >> 1); c = (k2 & 1) * 17; }
            *(u32x4*)(lds + cg * CGS + slotof(r, c) * 16) = z;
        }
    }
    __syncthreads();
    // ---- phase 2: periodic copies (sources are original interior values) ----
    if (tid < 240) {
        int pair = tid >> 3, cg = tid & 7;
        int sa = slotof(PSR[pair], PSC[pair]);
        int da = slotof(PDR[pair], PDC[pair]);
        u32x4 v = *(const u32x4*)(lds + cg * CGS + sa * 16);
        *(u32x4*)(lds + cg * CGS + da * 16) = v;
    }
    __syncthreads();

    // ---- compute ----
    f32x4 acc[3][4];
#pragma unroll
    for (int d2 = 0; d2 < 3; ++d2)
#pragma unroll
        for (int n2 = 0; n2 < 4; ++n2) acc[d2][n2] = (f32x4){0.f, 0.f, 0.f, 0.f};

    const int bbase = q * CGS + io * 288 + j * 16;
    const uint16_t* pwl = pw + (size_t)l * 8;

    constexpr uint32_t RM[16] = {0x0008, 0x003C, 0x00FC, 0x01FE, 0x07FF, 0x0FFF, 0x0FFF, 0x1FFE,
                                 0x3FFE, 0xBFFC, 0xBFFC, 0x7FF8, 0xFFF0, 0x3FC0, 0x3F80, 0x1E00};
    const int odd = j & 1;

#define BRD(dr, dc) __builtin_bit_cast(bf16x8, *(const u32x4*)(lb + ((dc) & 1) * 2592 + (4 * nt + (dr)) * 144 + ((dc) >> 1) * 16))
#define DO_MFMAS()                                                                             \
            bf16x8 b00 = BRD(0, 0);                                                            \
            acc[0][nt] = __builtin_amdgcn_mfma_f32_16x16x32_bf16(aw[0], b00, acc[0][nt], 0, 0, 0); \
            bf16x8 b01 = BRD(0, 1);                                                            \
            acc[0][nt] = __builtin_amdgcn_mfma_f32_16x16x32_bf16(aw[1], b01, acc[0][nt], 0, 0, 0); \
            bf16x8 b11 = BRD(1, 1);                                                            \
            acc[0][nt] = __builtin_amdgcn_mfma_f32_16x16x32_bf16(aw[2],  b11, acc[0][nt], 0, 0, 0); \
            acc[1][nt] = __builtin_amdgcn_mfma_f32_16x16x32_bf16(aw[5],  b11, acc[1][nt], 0, 0, 0); \
            acc[2][nt] = __builtin_amdgcn_mfma_f32_16x16x32_bf16(aw[10], b11, acc[2][nt], 0, 0, 0); \
            bf16x8 b20 = BRD(2, 0);                                                            \
            acc[1][nt] = __builtin_amdgcn_mfma_f32_16x16x32_bf16(aw[6],  b20, acc[1][nt], 0, 0, 0); \
            bf16x8 b21 = BRD(2, 1);                                                            \
            acc[0][nt] = __builtin_amdgcn_mfma_f32_16x16x32_bf16(aw[3],  b21, acc[0][nt], 0, 0, 0); \
            acc[1][nt] = __builtin_amdgcn_mfma_f32_16x16x32_bf16(aw[7],  b21, acc[1][nt], 0, 0, 0); \
            acc[2][nt] = __builtin_amdgcn_mfma_f32_16x16x32_bf16(aw[11], b21, acc[2][nt], 0, 0, 0); \
            bf16x8 b22 = BRD(2, 2);                                                            \
            acc[0][nt] = __builtin_amdgcn_mfma_f32_16x16x32_bf16(aw[4],  b22, acc[0][nt], 0, 0, 0); \
            acc[1][nt] = __builtin_amdgcn_mfma_f32_16x16x32_bf16(aw[8],  b22, acc[1][nt], 0, 0, 0); \
            acc[2][nt] = __builtin_amdgcn_mfma_f32_16x16x32_bf16(aw[12], b22, acc[2][nt], 0, 0, 0); \
            bf16x8 b23 = BRD(2, 3);                                                            \
            acc[2][nt] = __builtin_amdgcn_mfma_f32_16x16x32_bf16(aw[13], b23, acc[2][nt], 0, 0, 0); \
            bf16x8 b31 = BRD(3, 1);                                                            \
            acc[1][nt] = __builtin_amdgcn_mfma_f32_16x16x32_bf16(aw[9],  b31, acc[1][nt], 0, 0, 0); \
            bf16x8 b33 = BRD(3, 3);                                                            \
            acc[2][nt] = __builtin_amdgcn_mfma_f32_16x16x32_bf16(aw[14], b33, acc[2][nt], 0, 0, 0);

    // kk = 0: pure MFMA
    {
        bf16x8 aw[15];
#pragma unroll
        for (int f2 = 0; f2 < 15; ++f2) {
            u32x4 t = *(const u32x4*)(pwl + (size_t)((f2 * 2 + 0) * 4 + wid) * 512);
            aw[f2] = __builtin_bit_cast(bf16x8, t);
        }
        const uint8_t* lb = lds + bbase;
#pragma unroll
        for (int nt = 0; nt < 4; ++nt) {
            DO_MFMAS()
        }
    }
    // kk = 1: per-nt MFMA + fused epilogue store (spreads VMEM stores across compute)
    {
        bf16x8 aw[15];
#pragma unroll
        for (int f2 = 0; f2 < 15; ++f2) {
            u32x4 t = *(const u32x4*)(pwl + (size_t)((f2 * 2 + 1) * 4 + wid) * 512);
            aw[f2] = __builtin_bit_cast(bf16x8, t);
        }
        const uint8_t* lb = lds + 4 * CGS + bbase;
#pragma unroll
        for (int nt = 0; nt < 4; ++nt) {
            DO_MFMAS()
            // ---- epilogue for this nt ----
            const int row_e = 4 * nt + 2 * io;
            const uint32_t me = io ? RM[4 * nt + 2] : RM[4 * nt + 0];
            const uint32_t mo = io ? RM[4 * nt + 3] : RM[4 * nt + 1];
            const uint32_t be  = (me >> (2 * j)) & 1u;
            const uint32_t bo0 = (mo >> (2 * j)) & 1u;
            const uint32_t bo1 = (mo >> (2 * j + 1)) & 1u;
#pragma unroll
            for (int r = 0; r < 4; ++r) {
                int o = ob + r;
                float up = acc[0][nt][r] + bias0[r];
                float lf = acc[1][nt][r] + bias1[r];
                float rt = acc[2][nt][r] + bias2[r];
                up = be  ? up : 0.f;
                lf = bo0 ? lf : 0.f;
                rt = bo1 ? rt : 0.f;
                float up_o = __shfl_xor(up, 1);
                float lf_o = __shfl_xor(lf, 1);
                float rt_o = __shfl_xor(rt, 1);
                f32x4 v;
                v[0] = odd ? lf_o : up;
                v[1] = odd ? rt_o : 0.f;
                v[2] = odd ? lf   : up_o;
                v[3] = odd ? rt   : 0.f;
                float* p = out + (((size_t)b * 64 + o) * 256 + (row_e + odd) * 16 + 4 * (j >> 1));
                __builtin_nontemporal_store(v, (f32x4*)p);
            }
        }
    }
#undef DO_MFMAS
#undef BRD
}

extern "C" void kernel_launch(void* const* d_in, const int* in_sizes, int n_in,
                              void* d_out, int out_size, void* d_ws, size_t ws_size,
                              hipStream_t stream) {
    const float* x  = (const float*)d_in[0];
    const float* wu = (const float*)d_in[1];
    const float* bu = (const float*)d_in[2];
    const float* wl = (const float*)d_in[3];
    const float* bl = (const float*)d_in[4];
    const float* wr = (const float*)d_in[5];
    const float* br = (const float*)d_in[6];
    float* out   = (float*)d_out;
    uint16_t* pw = (uint16_t*)d_ws;          // 245,760 B of packed bf16 weights

    int B = in_sizes[0] / 16384;             // 2048
    pack_w<<<(NFRAG + 255) / 256, 256, 0, stream>>>(wu, wl, wr, pw);
    kagome_main<<<B, 256, 0, stream>>>(x, pw, bu, bl, br, out);
}